// Round 4
// baseline (616.300 us; speedup 1.0000x reference)
//
#include <hip/hip_runtime.h>
#include <stdint.h>

#define NN 8192
#define FIN 512
#define FOUT 256
#define ALPHA 0.2f
#define KSPLIT 8
#define JT 64
#define NT ((NN / KSPLIT) / JT)   // 16 iterations per block

typedef float f32x4 __attribute__((ext_vector_type(4)));
typedef short s16x8 __attribute__((ext_vector_type(8)));
typedef uint32_t u32x4 __attribute__((ext_vector_type(4)));

__device__ __forceinline__ uint16_t f2bf(float f) {
  union { float f; uint32_t u; } v; v.f = f;
  uint32_t u = v.u + 0x7fffu + ((v.u >> 16) & 1u);
  return (uint16_t)(u >> 16);
}

// ---------------- 1. wa1/wa2 = W @ a1 / a2 (fp32) ----------------
__global__ __launch_bounds__(256) void k_wa(const float* __restrict__ W,
                                            const float* __restrict__ a,
                                            float* __restrict__ wa1, float* __restrict__ wa2) {
  __shared__ float a1[256], a2[256];
  int tid = threadIdx.x;
  a1[tid] = a[tid];
  a2[tid] = a[tid + 256];
  __syncthreads();
  int m = blockIdx.x * 256 + tid;   // 0..511
  const float* wrow = W + (size_t)m * FOUT;
  float s1 = 0.f, s2 = 0.f;
  for (int k = 0; k < FOUT; k += 4) {
    f32x4 v = *(const f32x4*)(wrow + k);
#pragma unroll
    for (int i = 0; i < 4; i++) {
      s1 += v[i] * a1[k + i];
      s2 += v[i] * a2[k + i];
    }
  }
  wa1[m] = s1; wa2[m] = s2;
}

// ---------------- 2. f1/f2 + exp tables (epack = bf16 pair) + x->bf16 ----------------
__global__ __launch_bounds__(256) void k_f1f2(const float* __restrict__ x,
                                              const float* __restrict__ wa1,
                                              const float* __restrict__ wa2,
                                              float* __restrict__ f1, float* __restrict__ f2,
                                              float* __restrict__ e1p, float* __restrict__ e1n,
                                              uint32_t* __restrict__ epack,
                                              uint16_t* __restrict__ xb,
                                              float* __restrict__ l_arr) {
  __shared__ float s1[512], s2[512];
  int tid = threadIdx.x;
  if (tid < 4) l_arr[blockIdx.x * 4 + tid] = 0.f;
  s1[tid] = wa1[tid]; s1[tid + 256] = wa1[tid + 256];
  s2[tid] = wa2[tid]; s2[tid + 256] = wa2[tid + 256];
  __syncthreads();
  int w = tid >> 6, l = tid & 63;
  int row = blockIdx.x * 4 + w;
  const float* xr = x + (size_t)row * FIN + l * 8;
  f32x4 v0 = *(const f32x4*)xr;
  f32x4 v1 = *(const f32x4*)(xr + 4);
  uint4 pk;
  pk.x = (uint32_t)f2bf(v0[0]) | ((uint32_t)f2bf(v0[1]) << 16);
  pk.y = (uint32_t)f2bf(v0[2]) | ((uint32_t)f2bf(v0[3]) << 16);
  pk.z = (uint32_t)f2bf(v1[0]) | ((uint32_t)f2bf(v1[1]) << 16);
  pk.w = (uint32_t)f2bf(v1[2]) | ((uint32_t)f2bf(v1[3]) << 16);
  *(uint4*)(xb + (size_t)row * FIN + l * 8) = pk;
  int kb = l * 8;
  float d1 = 0.f, d2 = 0.f;
#pragma unroll
  for (int i = 0; i < 4; i++) {
    d1 += v0[i] * s1[kb + i] + v1[i] * s1[kb + 4 + i];
    d2 += v0[i] * s2[kb + i] + v1[i] * s2[kb + 4 + i];
  }
#pragma unroll
  for (int off = 32; off; off >>= 1) {
    d1 += __shfl_down(d1, off);
    d2 += __shfl_down(d2, off);
  }
  if (l == 0) {
    f1[row] = d1; f2[row] = d2;
    e1p[row] = __expf(d1);          // exp(f1) (i side, f32)
    e1n[row] = __expf(ALPHA * d1);  // exp(0.2 f1)
    // j side packed as bf16 pair: hi = exp(f2), lo = exp(0.2 f2)
    epack[row] = ((uint32_t)f2bf(__expf(d2)) << 16) | (uint32_t)f2bf(__expf(ALPHA * d2));
  }
}

// ---------------- 3. wt[f][k] = bf16(W[k][f]) ----------------
__global__ __launch_bounds__(256) void k_prep_wt(const float* __restrict__ W,
                                                 uint16_t* __restrict__ wt) {
  int idx = blockIdx.x * 256 + threadIdx.x;
  int f  = idx >> 7;
  int k4 = (idx & 127) * 4;
  ushort4 o;
  o.x = f2bf(W[(size_t)(k4 + 0) * FOUT + f]);
  o.y = f2bf(W[(size_t)(k4 + 1) * FOUT + f]);
  o.z = f2bf(W[(size_t)(k4 + 2) * FOUT + f]);
  o.w = f2bf(W[(size_t)(k4 + 3) * FOUT + f]);
  *(ushort4*)(wt + (size_t)f * FIN + k4) = o;
}

// ---------------- 4. h = xb @ W  (bf16 MFMA, 64x64 tiles -> 512 blocks = 2/CU) ----------------
__global__ __launch_bounds__(256, 2) void k_gemm_h(const uint16_t* __restrict__ xb,
                                                   const uint16_t* __restrict__ wt,
                                                   uint16_t* __restrict__ h) {
  __shared__ uint16_t Xs[64][40];
  __shared__ uint16_t Ws[64][40];
  int i0 = blockIdx.x * 64;
  int f0 = blockIdx.y * 64;
  int tid = threadIdx.x;
  int w = tid >> 6, l = tid & 63;
  int q = l >> 4, r16 = l & 15;
  f32x4 acc[4];
#pragma unroll
  for (int b = 0; b < 4; b++) acc[b] = (f32x4)0.f;

  int srow = tid >> 2, sch = tid & 3;
  for (int k0 = 0; k0 < FIN; k0 += 32) {
    uint4 xv = *(const uint4*)(xb + (size_t)(i0 + srow) * FIN + k0 + sch * 8);
    uint4 wv = *(const uint4*)(wt + (size_t)(f0 + srow) * FIN + k0 + sch * 8);
    *(uint4*)(&Xs[srow][sch * 8]) = xv;
    *(uint4*)(&Ws[srow][sch * 8]) = wv;
    __syncthreads();
    s16x8 A = *(const s16x8*)(&Xs[w * 16 + r16][q * 8]);
    s16x8 B[4];
#pragma unroll
    for (int b = 0; b < 4; b++) B[b] = *(const s16x8*)(&Ws[b * 16 + r16][q * 8]);
#pragma unroll
    for (int b = 0; b < 4; b++)
      acc[b] = __builtin_amdgcn_mfma_f32_16x16x32_bf16(A, B[b], acc[b], 0, 0, 0);
    __syncthreads();
  }
#pragma unroll
  for (int b = 0; b < 4; b++)
#pragma unroll
    for (int reg = 0; reg < 4; reg++) {
      int row = i0 + w * 16 + q * 4 + reg;
      int col = f0 + b * 16 + r16;
      h[(size_t)row * FOUT + col] = f2bf(acc[b][reg]);
    }
}

// ---------------- 5. transpose h -> ht[f][j] (bf16) ----------------
__global__ __launch_bounds__(256) void k_transpose(const uint16_t* __restrict__ h,
                                                   uint16_t* __restrict__ ht) {
  __shared__ uint16_t T[64][72];
  int i0 = blockIdx.x * 64, f0 = blockIdx.y * 64;
  int tid = threadIdx.x;
#pragma unroll
  for (int p = 0; p < 2; p++) {
    int idx = tid + p * 256;
    int r = idx >> 3, c8 = idx & 7;
    uint4 v = *(const uint4*)(h + (size_t)(i0 + r) * FOUT + f0 + c8 * 8);
    *(uint4*)(&T[r][c8 * 8]) = v;
  }
  __syncthreads();
#pragma unroll
  for (int p = 0; p < 2; p++) {
    int idx = tid + p * 256;
    int fr = idx >> 3, ic8 = idx & 7;
    s16x8 v;
#pragma unroll
    for (int j = 0; j < 8; j++) v[j] = (short)T[ic8 * 8 + j][fr];
    *(s16x8*)(ht + (size_t)(f0 + fr) * NN + i0 + ic8 * 8) = v;
  }
}

// ---------------- 6. fused scores -> P(bf16) -> P @ h (MFMA), split-K ----------------
// B-operand loaded DIRECTLY from ht (per-wave rows, L2-hit) -> no Hs LDS.
// Ps double-buffered -> single barrier/iter. adj prefetched one iter ahead.
#define ATT_ITER(S, CUR, NXT, PB) { \
  int j0 = jbase + (S) * JT; \
  f32x4 F_[4]; \
  uint4 E_[4]; \
  const float* fp_ = f2 + j0 + pch * 16; \
  const uint4* ep_ = (const uint4*)(epack + j0 + pch * 16); \
  _Pragma("unroll") for (int t = 0; t < 4; ++t) F_[t] = *(const f32x4*)(fp_ + t * 4); \
  _Pragma("unroll") for (int t = 0; t < 4; ++t) E_[t] = ep_[t]; \
  s16x8 pv0, pv1; \
  _Pragma("unroll") for (int t = 0; t < 4; ++t) { \
    _Pragma("unroll") for (int k2 = 0; k2 < 4; ++k2) { \
      uint32_t wrd = ((const uint32_t*)&E_[t])[k2]; \
      float ep2 = __uint_as_float(wrd & 0xffff0000u); \
      float en2 = __uint_as_float(wrd << 16); \
      bool c_ = F_[t][k2] >= negf1; \
      float p_ = (CUR[t][k2] != 0u) ? (c_ ? e1pi * ep2 : e1ni * en2) : 1.0f; \
      lsum += p_; \
      uint16_t pb_ = f2bf(p_); \
      int jj = t * 4 + k2; \
      if (jj < 8) pv0[jj] = (short)pb_; else pv1[jj - 8] = (short)pb_; \
    } \
  } \
  *(s16x8*)(&Ps[PB][prow][pch * 16]) = pv0; \
  *(s16x8*)(&Ps[PB][prow][pch * 16 + 8]) = pv1; \
  if ((S) + 1 < NT) { \
    const u32x4* ap_ = (const u32x4*)(arow + jbase + ((S) + 1) * JT); \
    _Pragma("unroll") for (int t = 0; t < 4; ++t) NXT[t] = ap_[t]; \
  } \
  __syncthreads(); \
  for (int c = 0; c < 2; ++c) { \
    s16x8 Af[4], Bf[4]; \
    _Pragma("unroll") for (int b = 0; b < 4; ++b) \
      Bf[b] = *(const s16x8*)(hb + (size_t)(b * 16) * NN + j0 + c * 32); \
    _Pragma("unroll") for (int a = 0; a < 4; ++a) \
      Af[a] = *(const s16x8*)(&Ps[PB][a * 16 + r16][c * 32 + q * 8]); \
    _Pragma("unroll") for (int a = 0; a < 4; ++a) { \
      _Pragma("unroll") for (int b = 0; b < 4; ++b) \
        acc[a][b] = __builtin_amdgcn_mfma_f32_16x16x32_bf16(Af[a], Bf[b], acc[a][b], 0, 0, 0); \
    } \
  } \
}

__global__ __launch_bounds__(256, 3) void k_att(const int* __restrict__ adj,
                                                const uint16_t* __restrict__ ht,
                                                const float* __restrict__ f1,
                                                const float* __restrict__ f2,
                                                const float* __restrict__ e1p,
                                                const float* __restrict__ e1n,
                                                const uint32_t* __restrict__ epack,
                                                float* __restrict__ l_arr,
                                                float* __restrict__ part) {
  __shared__ uint16_t Ps[2][64][72];
  int i0 = blockIdx.x * 64;
  int jbase = blockIdx.y * (NN / KSPLIT);   // 1024-wide K slice
  int tid = threadIdx.x;
  int w = tid >> 6, l = tid & 63;
  int q = l >> 4, r16 = l & 15;
  int prow = tid >> 2, pch = tid & 3;
  float negf1 = -f1[i0 + prow];
  float e1pi = e1p[i0 + prow];
  float e1ni = e1n[i0 + prow];
  float lsum = 0.f;
  const int* arow = adj + (size_t)(i0 + prow) * NN + pch * 16;
  const uint16_t* hb = ht + (size_t)(w * 64 + r16) * NN + q * 8;
  f32x4 acc[4][4];
#pragma unroll
  for (int a = 0; a < 4; a++)
#pragma unroll
    for (int b = 0; b < 4; b++) acc[a][b] = (f32x4)0.f;

  u32x4 adv0[4], adv1[4];
  {
    const u32x4* ap_ = (const u32x4*)(arow + jbase);
#pragma unroll
    for (int t = 0; t < 4; ++t) adv0[t] = ap_[t];
  }
  for (int s = 0; s < NT; s += 2) {
    ATT_ITER(s,     adv0, adv1, 0)
    ATT_ITER(s + 1, adv1, adv0, 1)
  }

  lsum += __shfl_down(lsum, 2);
  lsum += __shfl_down(lsum, 1);
  if (pch == 0) atomicAdd(&l_arr[i0 + prow], lsum);

  float* pb = part + (size_t)blockIdx.y * ((size_t)NN * FOUT);
#pragma unroll
  for (int a = 0; a < 4; a++)
#pragma unroll
    for (int b = 0; b < 4; b++)
#pragma unroll
      for (int reg = 0; reg < 4; reg++) {
        int row = i0 + a * 16 + q * 4 + reg;
        int col = w * 64 + b * 16 + r16;
        pb[(size_t)row * FOUT + col] = acc[a][b][reg];
      }
}

// ---------------- 7. combine split-K partials, /l, ELU, fp32 out ----------------
__global__ __launch_bounds__(256) void k_combine(const float* __restrict__ part,
                                                 const float* __restrict__ l_arr,
                                                 float* __restrict__ out) {
  int idx = (blockIdx.x * 256 + threadIdx.x) * 4;
  float r = 1.0f / l_arr[idx >> 8];
  f32x4 sum = (f32x4)0.f;
#pragma unroll
  for (int p = 0; p < KSPLIT; p++)
    sum += *(const f32x4*)(part + (size_t)p * (NN * FOUT) + idx);
  f32x4 o;
#pragma unroll
  for (int i = 0; i < 4; i++) {
    float v = sum[i] * r;
    o[i] = v > 0.f ? v : (__expf(v) - 1.f);
  }
  *(f32x4*)(out + idx) = o;
}

extern "C" void kernel_launch(void* const* d_in, const int* in_sizes, int n_in,
                              void* d_out, int out_size, void* d_ws, size_t ws_size,
                              hipStream_t stream) {
  const float* x   = (const float*)d_in[0];
  const int*   adj = (const int*)d_in[1];
  const float* W   = (const float*)d_in[2];
  const float* a   = (const float*)d_in[3];
  float* out = (float*)d_out;

  char* ws = (char*)d_ws;
  float*    wa1   = (float*)ws;                        // 512 f32
  float*    wa2   = wa1 + 512;                         // 512 f32
  float*    f1    = wa2 + 512;                         // 8192 f32
  float*    f2    = f1 + NN;                           // 8192 f32
  float*    l_arr = f2 + NN;                           // 8192 f32
  float*    e1p   = l_arr + NN;                        // 8192 f32
  float*    e1n   = e1p + NN;                          // 8192 f32
  uint32_t* epack = (uint32_t*)(e1n + NN);             // 8192 u32
  uint16_t* wt    = (uint16_t*)(epack + NN);           // 256*512 bf16 (256 KB)
  uint16_t* xb    = wt + (size_t)FOUT * FIN;           // 8192*512 bf16 (8 MB)
  uint16_t* h     = xb + (size_t)NN * FIN;             // 8192*256 bf16 (4 MB)
  uint16_t* ht    = h + (size_t)NN * FOUT;             // 256*8192 bf16 (4 MB)
  float*    part  = (float*)(ht + (size_t)NN * FOUT);  // KSPLIT * 8192*256 f32 (64 MB)

  k_wa<<<2, 256, 0, stream>>>(W, a, wa1, wa2);
  k_f1f2<<<NN / 4, 256, 0, stream>>>(x, wa1, wa2, f1, f2, e1p, e1n, epack, xb, l_arr);
  k_prep_wt<<<128, 256, 0, stream>>>(W, wt);
  k_gemm_h<<<dim3(NN / 64, FOUT / 64), 256, 0, stream>>>(xb, wt, h);
  k_transpose<<<dim3(NN / 64, FOUT / 64), 256, 0, stream>>>(h, ht);
  k_att<<<dim3(NN / 64, KSPLIT), 256, 0, stream>>>(adj, ht, f1, f2, e1p, e1n, epack, l_arr, part);
  k_combine<<<NN * FOUT / 1024, 256, 0, stream>>>(part, l_arr, out);
}

// Round 5
// 539.410 us; speedup vs baseline: 1.1425x; 1.1425x over previous
//
#include <hip/hip_runtime.h>
#include <stdint.h>

#define NN 8192
#define FIN 512
#define FOUT 256
#define ALPHA 0.2f
#define KSPLIT 4
#define JT 64
#define NT ((NN / KSPLIT) / JT)   // 32 iterations per block

typedef float f32x4 __attribute__((ext_vector_type(4)));
typedef short s16x8 __attribute__((ext_vector_type(8)));

__device__ __forceinline__ uint16_t f2bf(float f) {
  union { float f; uint32_t u; } v; v.f = f;
  uint32_t u = v.u + 0x7fffu + ((v.u >> 16) & 1u);
  return (uint16_t)(u >> 16);
}

// ---------------- 1. wa1/wa2 = W @ a1 / a2 (fp32) ----------------
__global__ __launch_bounds__(256) void k_wa(const float* __restrict__ W,
                                            const float* __restrict__ a,
                                            float* __restrict__ wa1, float* __restrict__ wa2) {
  __shared__ float a1[256], a2[256];
  int tid = threadIdx.x;
  a1[tid] = a[tid];
  a2[tid] = a[tid + 256];
  __syncthreads();
  int m = blockIdx.x * 256 + tid;   // 0..511
  const float* wrow = W + (size_t)m * FOUT;
  float s1 = 0.f, s2 = 0.f;
  for (int k = 0; k < FOUT; k += 4) {
    f32x4 v = *(const f32x4*)(wrow + k);
#pragma unroll
    for (int i = 0; i < 4; i++) {
      s1 += v[i] * a1[k + i];
      s2 += v[i] * a2[k + i];
    }
  }
  wa1[m] = s1; wa2[m] = s2;
}

// ---------------- 2. f1/f2 = x @ wa1/wa2 + x->bf16 + l_arr zero ----------------
__global__ __launch_bounds__(256) void k_f1f2(const float* __restrict__ x,
                                              const float* __restrict__ wa1,
                                              const float* __restrict__ wa2,
                                              float* __restrict__ f1, float* __restrict__ f2,
                                              uint16_t* __restrict__ xb,
                                              float* __restrict__ l_arr) {
  __shared__ float s1[512], s2[512];
  int tid = threadIdx.x;
  if (tid < 4) l_arr[blockIdx.x * 4 + tid] = 0.f;
  s1[tid] = wa1[tid]; s1[tid + 256] = wa1[tid + 256];
  s2[tid] = wa2[tid]; s2[tid + 256] = wa2[tid + 256];
  __syncthreads();
  int w = tid >> 6, l = tid & 63;
  int row = blockIdx.x * 4 + w;
  const float* xr = x + (size_t)row * FIN + l * 8;
  f32x4 v0 = *(const f32x4*)xr;
  f32x4 v1 = *(const f32x4*)(xr + 4);
  uint4 pk;
  pk.x = (uint32_t)f2bf(v0[0]) | ((uint32_t)f2bf(v0[1]) << 16);
  pk.y = (uint32_t)f2bf(v0[2]) | ((uint32_t)f2bf(v0[3]) << 16);
  pk.z = (uint32_t)f2bf(v1[0]) | ((uint32_t)f2bf(v1[1]) << 16);
  pk.w = (uint32_t)f2bf(v1[2]) | ((uint32_t)f2bf(v1[3]) << 16);
  *(uint4*)(xb + (size_t)row * FIN + l * 8) = pk;
  int kb = l * 8;
  float d1 = 0.f, d2 = 0.f;
#pragma unroll
  for (int i = 0; i < 4; i++) {
    d1 += v0[i] * s1[kb + i] + v1[i] * s1[kb + 4 + i];
    d2 += v0[i] * s2[kb + i] + v1[i] * s2[kb + 4 + i];
  }
#pragma unroll
  for (int off = 32; off; off >>= 1) {
    d1 += __shfl_down(d1, off);
    d2 += __shfl_down(d2, off);
  }
  if (l == 0) { f1[row] = d1; f2[row] = d2; }
}

// ---------------- 3. wt[f][k] = bf16(W[k][f]) ----------------
__global__ __launch_bounds__(256) void k_prep_wt(const float* __restrict__ W,
                                                 uint16_t* __restrict__ wt) {
  int idx = blockIdx.x * 256 + threadIdx.x;
  int f  = idx >> 7;
  int k4 = (idx & 127) * 4;
  ushort4 o;
  o.x = f2bf(W[(size_t)(k4 + 0) * FOUT + f]);
  o.y = f2bf(W[(size_t)(k4 + 1) * FOUT + f]);
  o.z = f2bf(W[(size_t)(k4 + 2) * FOUT + f]);
  o.w = f2bf(W[(size_t)(k4 + 3) * FOUT + f]);
  *(ushort4*)(wt + (size_t)f * FIN + k4) = o;
}

// ---------------- 4. h = xb @ W  (bf16 MFMA, 64x64 tiles) ----------------
__global__ __launch_bounds__(256, 2) void k_gemm_h(const uint16_t* __restrict__ xb,
                                                   const uint16_t* __restrict__ wt,
                                                   uint16_t* __restrict__ h) {
  __shared__ uint16_t Xs[64][40];
  __shared__ uint16_t Ws[64][40];
  int i0 = blockIdx.x * 64;
  int f0 = blockIdx.y * 64;
  int tid = threadIdx.x;
  int w = tid >> 6, l = tid & 63;
  int q = l >> 4, r16 = l & 15;
  f32x4 acc[4];
#pragma unroll
  for (int b = 0; b < 4; b++) acc[b] = (f32x4)0.f;

  int srow = tid >> 2, sch = tid & 3;
  for (int k0 = 0; k0 < FIN; k0 += 32) {
    uint4 xv = *(const uint4*)(xb + (size_t)(i0 + srow) * FIN + k0 + sch * 8);
    uint4 wv = *(const uint4*)(wt + (size_t)(f0 + srow) * FIN + k0 + sch * 8);
    *(uint4*)(&Xs[srow][sch * 8]) = xv;
    *(uint4*)(&Ws[srow][sch * 8]) = wv;
    __syncthreads();
    s16x8 A = *(const s16x8*)(&Xs[w * 16 + r16][q * 8]);
    s16x8 B[4];
#pragma unroll
    for (int b = 0; b < 4; b++) B[b] = *(const s16x8*)(&Ws[b * 16 + r16][q * 8]);
#pragma unroll
    for (int b = 0; b < 4; b++)
      acc[b] = __builtin_amdgcn_mfma_f32_16x16x32_bf16(A, B[b], acc[b], 0, 0, 0);
    __syncthreads();
  }
#pragma unroll
  for (int b = 0; b < 4; b++)
#pragma unroll
    for (int reg = 0; reg < 4; reg++) {
      int row = i0 + w * 16 + q * 4 + reg;
      int col = f0 + b * 16 + r16;
      h[(size_t)row * FOUT + col] = f2bf(acc[b][reg]);
    }
}

// ---------------- 5. transpose h -> ht[f][j] (bf16) ----------------
__global__ __launch_bounds__(256) void k_transpose(const uint16_t* __restrict__ h,
                                                   uint16_t* __restrict__ ht) {
  __shared__ uint16_t T[64][72];
  int i0 = blockIdx.x * 64, f0 = blockIdx.y * 64;
  int tid = threadIdx.x;
#pragma unroll
  for (int p = 0; p < 2; p++) {
    int idx = tid + p * 256;
    int r = idx >> 3, c8 = idx & 7;
    uint4 v = *(const uint4*)(h + (size_t)(i0 + r) * FOUT + f0 + c8 * 8);
    *(uint4*)(&T[r][c8 * 8]) = v;
  }
  __syncthreads();
#pragma unroll
  for (int p = 0; p < 2; p++) {
    int idx = tid + p * 256;
    int fr = idx >> 3, ic8 = idx & 7;
    s16x8 v;
#pragma unroll
    for (int j = 0; j < 8; j++) v[j] = (short)T[ic8 * 8 + j][fr];
    *(s16x8*)(ht + (size_t)(f0 + fr) * NN + i0 + ic8 * 8) = v;
  }
}

// ---------------- 6. fused scores -> P(bf16) -> P @ h (MFMA), split-K ----------------
// Steady-state loop body has ZERO global loads on the critical path:
//  - adj + ht register-prefetched one iteration ahead, issued BEFORE the barrier;
//  - raw s_barrier + lgkmcnt(0) (no vmcnt drain) keeps prefetch in flight;
//  - f2 slice staged once in LDS;
//  - Ps double-buffered, Hs wave-private (each wave stages/reads its own 64 rows)
//    -> ONE barrier per iteration.
__global__ __launch_bounds__(256, 2) void k_att(const int* __restrict__ adj,
                                                const uint16_t* __restrict__ ht,
                                                const float* __restrict__ f1,
                                                const float* __restrict__ f2,
                                                float* __restrict__ l_arr,
                                                float* __restrict__ part) {
  __shared__ uint16_t Ps[2][64][72];   // 18 KB (double-buffered P tile)
  __shared__ uint16_t Hs[256][72];     // 36 KB (wave-private row ranges)
  __shared__ float Fs[NN / KSPLIT];    // 8 KB (f2 slice)
  int i0 = blockIdx.x * 64;
  int jbase = blockIdx.y * (NN / KSPLIT);   // 2048-wide K slice
  int tid = threadIdx.x;
  int w = tid >> 6, l = tid & 63;
  int q = l >> 4, r16 = l & 15;
  int prow = tid >> 2, pch = tid & 3;       // P-compute: 16 j per thread
  int hr8 = l >> 3, hc8 = l & 7;            // Hs staging (wave-private rows)
  float f1i = f1[i0 + prow];
  float lsum = 0.f;

  // stage f2 slice into LDS (one time)
  {
    f32x4 a0 = *(const f32x4*)(f2 + jbase + tid * 8);
    f32x4 a1 = *(const f32x4*)(f2 + jbase + tid * 8 + 4);
    *(f32x4*)(&Fs[tid * 8]) = a0;
    *(f32x4*)(&Fs[tid * 8 + 4]) = a1;
  }
  __syncthreads();

  f32x4 acc[4][4];
#pragma unroll
  for (int a = 0; a < 4; a++)
#pragma unroll
    for (int b = 0; b < 4; b++) acc[a][b] = (f32x4)0.f;

  const int* arow = adj + (size_t)(i0 + prow) * NN + jbase + pch * 16;
  const uint16_t* hrow = ht + (size_t)(w * 64 + hr8) * NN + jbase + hc8 * 8;

  // prologue: issue iter-0 prefetch (after the syncthreads so it isn't drained)
  int4 adv[4];
  uint4 hv[8];
#pragma unroll
  for (int t = 0; t < 4; ++t) adv[t] = *(const int4*)(arow + t * 4);
#pragma unroll
  for (int p = 0; p < 8; ++p) hv[p] = *(const uint4*)(hrow + (size_t)p * 8 * NN);

  for (int s = 0; s < NT; ++s) {
    int jl = s * JT;
    // ---- P-compute from prefetched adv + LDS f2 ----
    f32x4 F0 = *(const f32x4*)(&Fs[jl + pch * 16]);
    f32x4 F1 = *(const f32x4*)(&Fs[jl + pch * 16 + 4]);
    f32x4 F2 = *(const f32x4*)(&Fs[jl + pch * 16 + 8]);
    f32x4 F3 = *(const f32x4*)(&Fs[jl + pch * 16 + 12]);
    s16x8 pv0, pv1;
#define PC(dst, kk, Ac, Fc) { float s_ = f1i + (Fc); float e_ = s_ > 0.f ? s_ : ALPHA * s_; \
      float p_ = ((Ac) != 0) ? __expf(e_) : 1.0f; lsum += p_; dst[kk] = (short)f2bf(p_); }
    PC(pv0, 0, adv[0].x, F0[0]) PC(pv0, 1, adv[0].y, F0[1])
    PC(pv0, 2, adv[0].z, F0[2]) PC(pv0, 3, adv[0].w, F0[3])
    PC(pv0, 4, adv[1].x, F1[0]) PC(pv0, 5, adv[1].y, F1[1])
    PC(pv0, 6, adv[1].z, F1[2]) PC(pv0, 7, adv[1].w, F1[3])
    PC(pv1, 0, adv[2].x, F2[0]) PC(pv1, 1, adv[2].y, F2[1])
    PC(pv1, 2, adv[2].z, F2[2]) PC(pv1, 3, adv[2].w, F2[3])
    PC(pv1, 4, adv[3].x, F3[0]) PC(pv1, 5, adv[3].y, F3[1])
    PC(pv1, 6, adv[3].z, F3[2]) PC(pv1, 7, adv[3].w, F3[3])
#undef PC
    uint16_t (*Pc)[72] = Ps[s & 1];
    *(s16x8*)(&Pc[prow][pch * 16]) = pv0;
    *(s16x8*)(&Pc[prow][pch * 16 + 8]) = pv1;
    // ---- Hs write (wave-private rows; hv from last iter's prefetch) ----
#pragma unroll
    for (int p = 0; p < 8; ++p)
      *(uint4*)(&Hs[w * 64 + p * 8 + hr8][hc8 * 8]) = hv[p];
    // ---- issue next-iter prefetch (stays in flight across the barrier) ----
    if (s + 1 < NT) {
      int jn = jl + JT;
#pragma unroll
      for (int t = 0; t < 4; ++t) adv[t] = *(const int4*)(arow + jn + t * 4);
#pragma unroll
      for (int p = 0; p < 8; ++p) hv[p] = *(const uint4*)(hrow + (size_t)p * 8 * NN + jn);
    }
    // ---- no-drain barrier: wait LDS writes only, NOT the vmcnt prefetch ----
    asm volatile("s_waitcnt lgkmcnt(0)" ::: "memory");
    __builtin_amdgcn_s_barrier();
    asm volatile("" ::: "memory");
    // ---- MFMA phase ----
#pragma unroll
    for (int c = 0; c < 2; ++c) {
      s16x8 Af[4], Bf[4];
#pragma unroll
      for (int a = 0; a < 4; ++a) Af[a] = *(const s16x8*)(&Pc[a * 16 + r16][c * 32 + q * 8]);
#pragma unroll
      for (int b = 0; b < 4; ++b) Bf[b] = *(const s16x8*)(&Hs[w * 64 + b * 16 + r16][c * 32 + q * 8]);
#pragma unroll
      for (int a = 0; a < 4; ++a)
#pragma unroll
        for (int b = 0; b < 4; ++b)
          acc[a][b] = __builtin_amdgcn_mfma_f32_16x16x32_bf16(Af[a], Bf[b], acc[a][b], 0, 0, 0);
    }
    // no trailing barrier needed: Ps is double-buffered, Hs is wave-private
  }

  // reduce lsum over the 4 lanes sharing prow
  lsum += __shfl_down(lsum, 2);
  lsum += __shfl_down(lsum, 1);
  if (pch == 0) atomicAdd(&l_arr[i0 + prow], lsum);

  float* pb = part + (size_t)blockIdx.y * ((size_t)NN * FOUT);
#pragma unroll
  for (int a = 0; a < 4; a++)
#pragma unroll
    for (int b = 0; b < 4; b++)
#pragma unroll
      for (int reg = 0; reg < 4; reg++) {
        int row = i0 + a * 16 + q * 4 + reg;
        int col = w * 64 + b * 16 + r16;
        pb[(size_t)row * FOUT + col] = acc[a][b][reg];
      }
}

// ---------------- 7. combine split-K partials, /l, ELU, fp32 out ----------------
__global__ __launch_bounds__(256) void k_combine(const float* __restrict__ part,
                                                 const float* __restrict__ l_arr,
                                                 float* __restrict__ out) {
  int idx = (blockIdx.x * 256 + threadIdx.x) * 4;
  float r = 1.0f / l_arr[idx >> 8];
  f32x4 sum = (f32x4)0.f;
#pragma unroll
  for (int p = 0; p < KSPLIT; p++)
    sum += *(const f32x4*)(part + (size_t)p * (NN * FOUT) + idx);
  f32x4 o;
#pragma unroll
  for (int i = 0; i < 4; i++) {
    float v = sum[i] * r;
    o[i] = v > 0.f ? v : (__expf(v) - 1.f);
  }
  *(f32x4*)(out + idx) = o;
}

extern "C" void kernel_launch(void* const* d_in, const int* in_sizes, int n_in,
                              void* d_out, int out_size, void* d_ws, size_t ws_size,
                              hipStream_t stream) {
  const float* x   = (const float*)d_in[0];
  const int*   adj = (const int*)d_in[1];
  const float* W   = (const float*)d_in[2];
  const float* a   = (const float*)d_in[3];
  float* out = (float*)d_out;

  char* ws = (char*)d_ws;
  float*    wa1   = (float*)ws;                        // 512 f32
  float*    wa2   = wa1 + 512;                         // 512 f32
  float*    f1    = wa2 + 512;                         // 8192 f32
  float*    f2    = f1 + NN;                           // 8192 f32
  float*    l_arr = f2 + NN;                           // 8192 f32
  uint16_t* wt    = (uint16_t*)(l_arr + NN);           // 256*512 bf16 (256 KB)
  uint16_t* xb    = wt + (size_t)FOUT * FIN;           // 8192*512 bf16 (8 MB)
  uint16_t* h     = xb + (size_t)NN * FIN;             // 8192*256 bf16 (4 MB)
  uint16_t* ht    = h + (size_t)NN * FOUT;             // 256*8192 bf16 (4 MB)
  float*    part  = (float*)(ht + (size_t)NN * FOUT);  // KSPLIT * 8192*256 f32 (32 MB)

  k_wa<<<2, 256, 0, stream>>>(W, a, wa1, wa2);
  k_f1f2<<<NN / 4, 256, 0, stream>>>(x, wa1, wa2, f1, f2, xb, l_arr);
  k_prep_wt<<<128, 256, 0, stream>>>(W, wt);
  k_gemm_h<<<dim3(NN / 64, FOUT / 64), 256, 0, stream>>>(xb, wt, h);
  k_transpose<<<dim3(NN / 64, FOUT / 64), 256, 0, stream>>>(h, ht);
  k_att<<<dim3(NN / 64, KSPLIT), 256, 0, stream>>>(adj, ht, f1, f2, l_arr, part);
  k_combine<<<NN * FOUT / 1024, 256, 0, stream>>>(part, l_arr, out);
}